// Round 5
// baseline (116.116 us; speedup 1.0000x reference)
//
#include <hip/hip_runtime.h>
#include <hip/hip_bf16.h>

#define N_NODES 8192
#define N_EDGES 131072
#define LN_EPS  1e-5f

typedef __attribute__((ext_vector_type(8))) short bf16x8;
typedef __attribute__((ext_vector_type(4))) float f32x4;

__device__ __forceinline__ float silu_f(float x) {
    return x / (1.0f + __expf(-x));
}

// fp32 -> bf16 RNE (scalar)
__device__ __forceinline__ unsigned short f2bf(float x) {
    union { float f; unsigned int u; } v; v.f = x;
    unsigned int r = v.u + 0x7FFFu + ((v.u >> 16) & 1u);
    return (unsigned short)(r >> 16);
}
__device__ __forceinline__ float bf2f(unsigned short u) {
    union { float f; unsigned int x; } v; v.x = ((unsigned int)u) << 16;
    return v.f;
}
// fp32 pair -> packed bf16x2 via v_cvt_pk_bf16_f32
__device__ __forceinline__ unsigned int pk2(float a, float b) {
    float2 t; t.x = a; t.y = b;
    union { __hip_bfloat162 h; unsigned int u; } v;
    v.h = __float22bfloat162_rn(t);
    return v.u;
}
__device__ __forceinline__ bf16x8 pack8(float4 u, float4 v) {
    union { bf16x8 b; unsigned int w[4]; } o;
    o.w[0] = pk2(u.x, u.y); o.w[1] = pk2(u.z, u.w);
    o.w[2] = pk2(v.x, v.y); o.w[3] = pk2(v.z, v.w);
    return o.b;
}
__device__ __forceinline__ f32x4 mfma16(bf16x8 a, bf16x8 b, f32x4 c) {
    return __builtin_amdgcn_mfma_f32_16x16x32_bf16(a, b, c, 0, 0, 0);
}

// ---------------------------------------------------------------------------
// Kernel 0: weight prep (bf16 transposes, n-major / r-major k-contiguous).
// ---------------------------------------------------------------------------
__global__ __launch_bounds__(256) void prep_kernel(
    const float* __restrict__ W_w, const float* __restrict__ W_t1,
    const float* __restrict__ W_t2, const float* __restrict__ Wvq,
    const float* __restrict__ Wvk0, const float* __restrict__ Wvk1,
    const float* __restrict__ Wvk2,
    unsigned short* __restrict__ Wtw, unsigned short* __restrict__ Wt1b,
    unsigned short* __restrict__ Wt2b, unsigned short* __restrict__ Wqt,
    unsigned short* __restrict__ Wk0t, unsigned short* __restrict__ Wk1t,
    unsigned short* __restrict__ Wk2t)
{
    int i = blockIdx.x * 256 + threadIdx.x;
    if (i < 16384) {
        int n = i >> 7, k = i & 127;
        Wt1b[i] = f2bf(W_t1[k * 128 + n]);
        Wt2b[i] = f2bf(W_t2[k * 128 + n]);
    }
    if (i < 4096) {
        { int n = i >> 5, k = i & 31; Wtw[i] = f2bf(W_w[k * 128 + n]); }
        int r = i >> 7, d = i & 127;
        Wqt[i]  = f2bf(Wvq [d * 32 + r]);
        Wk0t[i] = f2bf(Wvk0[d * 32 + r]);
        Wk1t[i] = f2bf(Wvk1[d * 32 + r]);
        Wk2t[i] = f2bf(Wvk2[d * 32 + r]);
    }
}

// ---------------------------------------------------------------------------
// Kernel 1: MFMA projections — barrier-free, no LDS (unchanged, verified).
// ---------------------------------------------------------------------------
template<int S, int LOFF>
__device__ __forceinline__ void proj_body(
    const float* __restrict__ X, const unsigned short* __restrict__ Wqt,
    const unsigned short* __restrict__ Wkt,
    unsigned short* __restrict__ eq, unsigned short* __restrict__ ek,
    int row0)
{
    const int tid  = threadIdx.x;
    const int lane = tid & 63;
    const int wv   = tid >> 6;
    const int l15  = lane & 15;
    const int lk   = lane >> 4;
    const int xrow = row0 + wv * 16 + l15;

    bf16x8 xf[4];
    #pragma unroll
    for (int kt = 0; kt < 4; ++kt) {
        const float* p = X + (size_t)xrow * 128 + kt * 32 + lk * 8;
        xf[kt] = pack8(*(const float4*)p, *(const float4*)(p + 4));
    }

    f32x4 qa[2], ka[2];
    #pragma unroll
    for (int h = 0; h < 2; ++h) {
        qa[h] = (f32x4){0.f, 0.f, 0.f, 0.f};
        ka[h] = (f32x4){0.f, 0.f, 0.f, 0.f};
    }
    #pragma unroll
    for (int kt = 0; kt < 4; ++kt) {
        #pragma unroll
        for (int h = 0; h < 2; ++h) {
            bf16x8 wq = *(const bf16x8*)&Wqt[(h * 16 + l15) * 128 + kt * 32 + lk * 8];
            bf16x8 wk = *(const bf16x8*)&Wkt[(h * 16 + l15) * 128 + kt * 32 + lk * 8];
            qa[h] = mfma16(wq, xf[kt], qa[h]);
            ka[h] = mfma16(wk, xf[kt], ka[h]);
        }
    }

    const int n = xrow / S;
    const int l = xrow % S + LOFF;
    const size_t base = (size_t)n * 480 + (size_t)l * 32;
    #pragma unroll
    for (int h = 0; h < 2; ++h) {
        int rb = h * 16 + lk * 4;
        union { ushort4 s; unsigned int u[2]; } pq, pk_;
        pq.u[0]  = pk2(qa[h][0], qa[h][1]); pq.u[1]  = pk2(qa[h][2], qa[h][3]);
        pk_.u[0] = pk2(ka[h][0], ka[h][1]); pk_.u[1] = pk2(ka[h][2], ka[h][3]);
        *(ushort4*)&eq[base + rb] = pq.s;
        *(ushort4*)&ek[base + rb] = pk_.s;
    }
}

__global__ __launch_bounds__(256) void proj_kernel(
    const float* __restrict__ X0, const float* __restrict__ X1,
    const float* __restrict__ X2,
    const unsigned short* __restrict__ Wqt,
    const unsigned short* __restrict__ Wk0t,
    const unsigned short* __restrict__ Wk1t,
    const unsigned short* __restrict__ Wk2t,
    unsigned short* __restrict__ eq, unsigned short* __restrict__ ek)
{
    const int b = blockIdx.x;
    if (b < 384)
        proj_body<3, 0>(X0, Wqt, Wk0t, eq, ek, b * 64);
    else if (b < 1024)
        proj_body<5, 3>(X1, Wqt, Wk1t, eq, ek, (b - 384) * 64);
    else
        proj_body<7, 8>(X2, Wqt, Wk2t, eq, ek, (b - 1024) * 64);
}

// ---------------------------------------------------------------------------
// Kernel 2: wn = LayerNorm(sum_l rej(q).rej(k)) — gather-heavy, no LDS
// (unchanged, verified).
// ---------------------------------------------------------------------------
__global__ __launch_bounds__(256) void wn_kernel(
    const unsigned short* __restrict__ eq, const unsigned short* __restrict__ ek,
    const float* __restrict__ r0, const float* __restrict__ r1,
    const float* __restrict__ r2, const int* __restrict__ eidx,
    const float* __restrict__ ln_g, const float* __restrict__ ln_b,
    unsigned short* __restrict__ wn)
{
    const int tid = threadIdx.x;
    const int r   = tid & 31;
    const int e   = blockIdx.x * 8 + (tid >> 5);
    const float g  = ln_g[r];
    const float bb = ln_b[r];
    const int nj = eidx[e];
    const int ni = eidx[N_EDGES + e];

    float q[15], k[15], rv[15];
    const unsigned short* qp = eq + (size_t)ni * 480 + r;
    const unsigned short* kp = ek + (size_t)nj * 480 + r;
    #pragma unroll
    for (int l = 0; l < 15; ++l) { q[l] = bf2f(qp[l * 32]); k[l] = bf2f(kp[l * 32]); }
    #pragma unroll
    for (int c = 0; c < 3; ++c) rv[c]     = r0[e * 3 + c];
    #pragma unroll
    for (int c = 0; c < 5; ++c) rv[3 + c] = r1[e * 5 + c];
    #pragma unroll
    for (int c = 0; c < 7; ++c) rv[8 + c] = r2[e * 7 + c];

    float dq, dk;
    dq = q[0]*rv[0] + q[1]*rv[1] + q[2]*rv[2];
    dk = k[0]*rv[0] + k[1]*rv[1] + k[2]*rv[2];
    #pragma unroll
    for (int l = 0; l < 3; ++l) { q[l] -= dq * rv[l]; k[l] -= dk * rv[l]; }
    dq = 0.f; dk = 0.f;
    #pragma unroll
    for (int l = 3; l < 8; ++l) { dq += q[l]*rv[l]; dk += k[l]*rv[l]; }
    #pragma unroll
    for (int l = 3; l < 8; ++l) { q[l] -= dq * rv[l]; k[l] -= dk * rv[l]; }
    dq = 0.f; dk = 0.f;
    #pragma unroll
    for (int l = 8; l < 15; ++l) { dq += q[l]*rv[l]; dk += k[l]*rv[l]; }
    #pragma unroll
    for (int l = 8; l < 15; ++l) { q[l] -= dq * rv[l]; k[l] -= dk * rv[l]; }

    float w = 0.f;
    #pragma unroll
    for (int l = 0; l < 15; ++l) w = fmaf(q[l], k[l], w);

    float s = w, s2 = w * w;
    s += __shfl_xor(s, 1);  s2 += __shfl_xor(s2, 1);
    s += __shfl_xor(s, 2);  s2 += __shfl_xor(s2, 2);
    s += __shfl_xor(s, 4);  s2 += __shfl_xor(s2, 4);
    s += __shfl_xor(s, 8);  s2 += __shfl_xor(s2, 8);
    s += __shfl_xor(s, 16); s2 += __shfl_xor(s2, 16);
    const float mu  = s * (1.f / 32.f);
    const float var = s2 * (1.f / 32.f) - mu * mu;
    const float wnv = (w - mu) * rsqrtf(var + LN_EPS) * g + bb;
    wn[(size_t)e * 32 + r] = f2bf(wnv);
}

// ---------------------------------------------------------------------------
// Kernel 3: barrier-free streaming MFMA GEMMs + epilogue, D[n][edge] layout.
// Each wave owns 32 edges; weights are the A-operand (rows = n), edges the
// B-operand (cols). Lane's 4 acc regs = 4 consecutive n for one edge ->
// float4 out stores, b64 h-panel writes. __launch_bounds__(256,4): 128 VGPR
// so the unrolled ct loops keep weight loads in flight. No __syncthreads.
// ---------------------------------------------------------------------------
__global__ __launch_bounds__(256, 4) void edge_kernel(
    const float* __restrict__ t_ij,
    const unsigned short* __restrict__ wn,
    const unsigned short* __restrict__ Wtw, const float* __restrict__ b_w,
    const unsigned short* __restrict__ Wt1, const float* __restrict__ b_t1,
    const unsigned short* __restrict__ Wt2, const float* __restrict__ b_t2,
    float* __restrict__ out)
{
    __shared__ __align__(16) unsigned short Hp[4][32 * 128];  // per-wave h panel

    const int tid  = threadIdx.x;
    const int lane = tid & 63;
    const int wv   = tid >> 6;
    const int l15  = lane & 15;
    const int lk   = lane >> 4;
    const int tile = (blockIdx.x * 4 + wv) * 32;
    char* hp = (char*)&Hp[wv][0];
    const int swz = (l15 & 7) << 4;

    // ---- B-frags: t_ij edges direct from global (lane = edge col) ----
    bf16x8 a1[4][2];
    #pragma unroll
    for (int kt = 0; kt < 4; ++kt)
        #pragma unroll
        for (int rt = 0; rt < 2; ++rt) {
            const float* p = t_ij + (size_t)(tile + rt * 16 + l15) * 128
                           + kt * 32 + lk * 8;
            a1[kt][rt] = pack8(*(const float4*)p, *(const float4*)(p + 4));
        }

    // ---- wn B-frags ----
    bf16x8 wnf[2];
    #pragma unroll
    for (int rt = 0; rt < 2; ++rt)
        wnf[rt] = *(const bf16x8*)&wn[(size_t)(tile + rt * 16 + l15) * 32 + lk * 8];

    // ---- GEMM1: h = silu(t @ W_t1 + b_t1) -> D[n][edge] -> h panel ----
    #pragma unroll
    for (int ct = 0; ct < 8; ++ct) {
        bf16x8 w1f[4];
        #pragma unroll
        for (int kt = 0; kt < 4; ++kt)
            w1f[kt] = *(const bf16x8*)&Wt1[(size_t)(ct * 16 + l15) * 128
                                           + kt * 32 + lk * 8];
        f32x4 ac0 = (f32x4){0.f, 0.f, 0.f, 0.f};
        f32x4 ac1 = (f32x4){0.f, 0.f, 0.f, 0.f};
        #pragma unroll
        for (int kt = 0; kt < 4; ++kt) {
            ac0 = mfma16(w1f[kt], a1[kt][0], ac0);
            ac1 = mfma16(w1f[kt], a1[kt][1], ac1);
        }
        const float4 bt1 = *(const float4*)&b_t1[ct * 16 + lk * 4];
        uint2 h0, h1;
        h0.x = pk2(silu_f(ac0[0] + bt1.x), silu_f(ac0[1] + bt1.y));
        h0.y = pk2(silu_f(ac0[2] + bt1.z), silu_f(ac0[3] + bt1.w));
        h1.x = pk2(silu_f(ac1[0] + bt1.x), silu_f(ac1[1] + bt1.y));
        h1.y = pk2(silu_f(ac1[2] + bt1.z), silu_f(ac1[3] + bt1.w));
        *(uint2*)(hp + ((l15 * 256 + ct * 32 + lk * 8) ^ swz)) = h0;
        *(uint2*)(hp + (((16 + l15) * 256 + ct * 32 + lk * 8) ^ swz)) = h1;
    }

    // ---- a2 B-frags from h panel (wave-local; compiler inserts lgkmcnt) ----
    bf16x8 a2[4][2];
    #pragma unroll
    for (int kt = 0; kt < 4; ++kt)
        #pragma unroll
        for (int rt = 0; rt < 2; ++rt)
            a2[kt][rt] = *(const bf16x8*)(hp +
                (((rt * 16 + l15) * 256 + kt * 64 + lk * 16) ^ swz));

    // ---- GEMM2 + dw + epilogue ----
    #pragma unroll
    for (int ct = 0; ct < 8; ++ct) {
        bf16x8 w2f[4];
        #pragma unroll
        for (int kt = 0; kt < 4; ++kt)
            w2f[kt] = *(const bf16x8*)&Wt2[(size_t)(ct * 16 + l15) * 128
                                           + kt * 32 + lk * 8];
        bf16x8 wwf = *(const bf16x8*)&Wtw[(ct * 16 + l15) * 32 + lk * 8];

        f32x4 o0 = (f32x4){0.f, 0.f, 0.f, 0.f};
        f32x4 o1 = (f32x4){0.f, 0.f, 0.f, 0.f};
        #pragma unroll
        for (int kt = 0; kt < 4; ++kt) {
            o0 = mfma16(w2f[kt], a2[kt][0], o0);
            o1 = mfma16(w2f[kt], a2[kt][1], o1);
        }
        f32x4 d0 = mfma16(wwf, wnf[0], (f32x4){0.f, 0.f, 0.f, 0.f});
        f32x4 d1 = mfma16(wwf, wnf[1], (f32x4){0.f, 0.f, 0.f, 0.f});

        const float4 bwv = *(const float4*)&b_w[ct * 16 + lk * 4];
        const float4 b2v = *(const float4*)&b_t2[ct * 16 + lk * 4];
        float4 s0, s1;
        s0.x = (d0[0] + bwv.x) * silu_f(o0[0] + b2v.x);
        s0.y = (d0[1] + bwv.y) * silu_f(o0[1] + b2v.y);
        s0.z = (d0[2] + bwv.z) * silu_f(o0[2] + b2v.z);
        s0.w = (d0[3] + bwv.w) * silu_f(o0[3] + b2v.w);
        s1.x = (d1[0] + bwv.x) * silu_f(o1[0] + b2v.x);
        s1.y = (d1[1] + bwv.y) * silu_f(o1[1] + b2v.y);
        s1.z = (d1[2] + bwv.z) * silu_f(o1[2] + b2v.z);
        s1.w = (d1[3] + bwv.w) * silu_f(o1[3] + b2v.w);
        *(float4*)&out[(size_t)(tile + l15) * 128 + ct * 16 + lk * 4]      = s0;
        *(float4*)&out[(size_t)(tile + 16 + l15) * 128 + ct * 16 + lk * 4] = s1;
    }
}

extern "C" void kernel_launch(void* const* d_in, const int* in_sizes, int n_in,
                              void* d_out, int out_size, void* d_ws, size_t ws_size,
                              hipStream_t stream) {
    (void)in_sizes; (void)n_in; (void)out_size; (void)ws_size;
    const float* X0   = (const float*)d_in[0];
    const float* X1   = (const float*)d_in[1];
    const float* X2   = (const float*)d_in[2];
    const float* t_ij = (const float*)d_in[3];
    const float* r0   = (const float*)d_in[4];
    const float* r1   = (const float*)d_in[5];
    const float* r2   = (const float*)d_in[6];
    const int*   eidx = (const int*)d_in[7];
    const float* Wvq  = (const float*)d_in[8];
    const float* Wvk0 = (const float*)d_in[9];
    const float* Wvk1 = (const float*)d_in[10];
    const float* Wvk2 = (const float*)d_in[11];
    const float* ln_g = (const float*)d_in[12];
    const float* ln_b = (const float*)d_in[13];
    const float* W_w  = (const float*)d_in[14];
    const float* b_w  = (const float*)d_in[15];
    const float* W_t1 = (const float*)d_in[16];
    const float* b_t1 = (const float*)d_in[17];
    const float* W_t2 = (const float*)d_in[18];
    const float* b_t2 = (const float*)d_in[19];
    float* out = (float*)d_out;

    unsigned short* eq   = (unsigned short*)d_ws;          // [N,15,32] bf16
    unsigned short* ek   = eq  + (size_t)N_NODES * 480;
    unsigned short* wn   = ek  + (size_t)N_NODES * 480;    // [E,32] bf16
    unsigned short* Wtw  = wn  + (size_t)N_EDGES * 32;
    unsigned short* Wt1b = Wtw  + 4096;
    unsigned short* Wt2b = Wt1b + 16384;
    unsigned short* Wqt  = Wt2b + 16384;
    unsigned short* Wk0t = Wqt  + 4096;
    unsigned short* Wk1t = Wk0t + 4096;
    unsigned short* Wk2t = Wk1t + 4096;

    prep_kernel<<<64, 256, 0, stream>>>(W_w, W_t1, W_t2, Wvq, Wvk0, Wvk1, Wvk2,
                                        Wtw, Wt1b, Wt2b, Wqt, Wk0t, Wk1t, Wk2t);
    proj_kernel<<<1920, 256, 0, stream>>>(X0, X1, X2, Wqt, Wk0t, Wk1t, Wk2t,
                                          eq, ek);
    wn_kernel<<<N_EDGES / 8, 256, 0, stream>>>(eq, ek, r0, r1, r2, eidx,
                                               ln_g, ln_b, wn);
    edge_kernel<<<N_EDGES / 128, 256, 0, stream>>>(t_ij, wn, Wtw, b_w,
                                                   Wt1b, b_t1, Wt2b, b_t2, out);
}

// Round 6
// 110.060 us; speedup vs baseline: 1.0550x; 1.0550x over previous
//
#include <hip/hip_runtime.h>
#include <hip/hip_bf16.h>

#define N_NODES 8192
#define N_EDGES 131072
#define LN_EPS  1e-5f

typedef __attribute__((ext_vector_type(8))) short bf16x8;
typedef __attribute__((ext_vector_type(4))) float f32x4;

// silu via v_rcp_f32: avoids IEEE div expansion (no fast-math in harness)
__device__ __forceinline__ float silu_f(float x) {
    return x * __builtin_amdgcn_rcpf(1.0f + __expf(-x));
}

// fp32 -> bf16 RNE (scalar)
__device__ __forceinline__ unsigned short f2bf(float x) {
    union { float f; unsigned int u; } v; v.f = x;
    unsigned int r = v.u + 0x7FFFu + ((v.u >> 16) & 1u);
    return (unsigned short)(r >> 16);
}
__device__ __forceinline__ float bf2f(unsigned short u) {
    union { float f; unsigned int x; } v; v.x = ((unsigned int)u) << 16;
    return v.f;
}
// fp32 pair -> packed bf16x2 via v_cvt_pk_bf16_f32
__device__ __forceinline__ unsigned int pk2(float a, float b) {
    float2 t; t.x = a; t.y = b;
    union { __hip_bfloat162 h; unsigned int u; } v;
    v.h = __float22bfloat162_rn(t);
    return v.u;
}
__device__ __forceinline__ bf16x8 pack8(float4 u, float4 v) {
    union { bf16x8 b; unsigned int w[4]; } o;
    o.w[0] = pk2(u.x, u.y); o.w[1] = pk2(u.z, u.w);
    o.w[2] = pk2(v.x, v.y); o.w[3] = pk2(v.z, v.w);
    return o.b;
}
__device__ __forceinline__ f32x4 mfma16(bf16x8 a, bf16x8 b, f32x4 c) {
    return __builtin_amdgcn_mfma_f32_16x16x32_bf16(a, b, c, 0, 0, 0);
}

// ---------------------------------------------------------------------------
// Kernel 0: weight prep (bf16 transposes, n-major / r-major k-contiguous).
// ---------------------------------------------------------------------------
__global__ __launch_bounds__(256) void prep_kernel(
    const float* __restrict__ W_w, const float* __restrict__ W_t1,
    const float* __restrict__ W_t2, const float* __restrict__ Wvq,
    const float* __restrict__ Wvk0, const float* __restrict__ Wvk1,
    const float* __restrict__ Wvk2,
    unsigned short* __restrict__ Wtw, unsigned short* __restrict__ Wt1b,
    unsigned short* __restrict__ Wt2b, unsigned short* __restrict__ Wqt,
    unsigned short* __restrict__ Wk0t, unsigned short* __restrict__ Wk1t,
    unsigned short* __restrict__ Wk2t)
{
    int i = blockIdx.x * 256 + threadIdx.x;
    if (i < 16384) {
        int n = i >> 7, k = i & 127;
        Wt1b[i] = f2bf(W_t1[k * 128 + n]);
        Wt2b[i] = f2bf(W_t2[k * 128 + n]);
    }
    if (i < 4096) {
        { int n = i >> 5, k = i & 31; Wtw[i] = f2bf(W_w[k * 128 + n]); }
        int r = i >> 7, d = i & 127;
        Wqt[i]  = f2bf(Wvq [d * 32 + r]);
        Wk0t[i] = f2bf(Wvk0[d * 32 + r]);
        Wk1t[i] = f2bf(Wvk1[d * 32 + r]);
        Wk2t[i] = f2bf(Wvk2[d * 32 + r]);
    }
}

// ---------------------------------------------------------------------------
// Kernel 1: MFMA projections — barrier-free, no LDS.
// Output layout NOW [n][r][l-pad16] bf16 (512 per node) so wn_kernel's
// gather is 2x bf16x8 per lane instead of 15 strided 2B loads.
// ---------------------------------------------------------------------------
template<int S, int LOFF>
__device__ __forceinline__ void proj_body(
    const float* __restrict__ X, const unsigned short* __restrict__ Wqt,
    const unsigned short* __restrict__ Wkt,
    unsigned short* __restrict__ eq, unsigned short* __restrict__ ek,
    int row0)
{
    const int tid  = threadIdx.x;
    const int lane = tid & 63;
    const int wv   = tid >> 6;
    const int l15  = lane & 15;
    const int lk   = lane >> 4;
    const int xrow = row0 + wv * 16 + l15;

    bf16x8 xf[4];
    #pragma unroll
    for (int kt = 0; kt < 4; ++kt) {
        const float* p = X + (size_t)xrow * 128 + kt * 32 + lk * 8;
        xf[kt] = pack8(*(const float4*)p, *(const float4*)(p + 4));
    }

    f32x4 qa[2], ka[2];
    #pragma unroll
    for (int h = 0; h < 2; ++h) {
        qa[h] = (f32x4){0.f, 0.f, 0.f, 0.f};
        ka[h] = (f32x4){0.f, 0.f, 0.f, 0.f};
    }
    #pragma unroll
    for (int kt = 0; kt < 4; ++kt) {
        #pragma unroll
        for (int h = 0; h < 2; ++h) {
            bf16x8 wq = *(const bf16x8*)&Wqt[(h * 16 + l15) * 128 + kt * 32 + lk * 8];
            bf16x8 wk = *(const bf16x8*)&Wkt[(h * 16 + l15) * 128 + kt * 32 + lk * 8];
            qa[h] = mfma16(wq, xf[kt], qa[h]);
            ka[h] = mfma16(wk, xf[kt], ka[h]);
        }
    }

    const int n = xrow / S;
    const int l = xrow % S + LOFF;
    const size_t base = (size_t)n * 512 + l;   // [n][r][l16]
    #pragma unroll
    for (int h = 0; h < 2; ++h) {
        #pragma unroll
        for (int j = 0; j < 4; ++j) {
            const int r = h * 16 + lk * 4 + j;
            eq[base + r * 16] = f2bf(qa[h][j]);
            ek[base + r * 16] = f2bf(ka[h][j]);
        }
    }
}

__global__ __launch_bounds__(256) void proj_kernel(
    const float* __restrict__ X0, const float* __restrict__ X1,
    const float* __restrict__ X2,
    const unsigned short* __restrict__ Wqt,
    const unsigned short* __restrict__ Wk0t,
    const unsigned short* __restrict__ Wk1t,
    const unsigned short* __restrict__ Wk2t,
    unsigned short* __restrict__ eq, unsigned short* __restrict__ ek)
{
    const int b = blockIdx.x;
    if (b < 384)
        proj_body<3, 0>(X0, Wqt, Wk0t, eq, ek, b * 64);
    else if (b < 1024)
        proj_body<5, 3>(X1, Wqt, Wk1t, eq, ek, (b - 384) * 64);
    else
        proj_body<7, 8>(X2, Wqt, Wk2t, eq, ek, (b - 1024) * 64);
}

// ---------------------------------------------------------------------------
// Kernel 2: wn = LayerNorm(sum_l rej(q).rej(k)). Gather is now 4x bf16x8
// coalesced loads per lane ([n][r][l16] layout). Half-wave (32 r) per edge.
// ---------------------------------------------------------------------------
__global__ __launch_bounds__(256) void wn_kernel(
    const unsigned short* __restrict__ eq, const unsigned short* __restrict__ ek,
    const float* __restrict__ r0, const float* __restrict__ r1,
    const float* __restrict__ r2, const int* __restrict__ eidx,
    const float* __restrict__ ln_g, const float* __restrict__ ln_b,
    unsigned short* __restrict__ wn)
{
    const int tid = threadIdx.x;
    const int r   = tid & 31;
    const int e   = blockIdx.x * 8 + (tid >> 5);
    const float g  = ln_g[r];
    const float bb = ln_b[r];
    const int nj = eidx[e];
    const int ni = eidx[N_EDGES + e];

    const unsigned short* qp = eq + (size_t)ni * 512 + r * 16;
    const unsigned short* kp = ek + (size_t)nj * 512 + r * 16;
    bf16x8 q0 = *(const bf16x8*)qp;
    bf16x8 q1 = *(const bf16x8*)(qp + 8);
    bf16x8 k0 = *(const bf16x8*)kp;
    bf16x8 k1 = *(const bf16x8*)(kp + 8);

    float q[15], k[15], rv[15];
    #pragma unroll
    for (int l = 0; l < 8; ++l) {
        q[l] = bf2f((unsigned short)q0[l]);
        k[l] = bf2f((unsigned short)k0[l]);
    }
    #pragma unroll
    for (int l = 8; l < 15; ++l) {
        q[l] = bf2f((unsigned short)q1[l - 8]);
        k[l] = bf2f((unsigned short)k1[l - 8]);
    }
    #pragma unroll
    for (int c = 0; c < 3; ++c) rv[c]     = r0[e * 3 + c];
    #pragma unroll
    for (int c = 0; c < 5; ++c) rv[3 + c] = r1[e * 5 + c];
    #pragma unroll
    for (int c = 0; c < 7; ++c) rv[8 + c] = r2[e * 7 + c];

    float dq, dk;
    dq = q[0]*rv[0] + q[1]*rv[1] + q[2]*rv[2];
    dk = k[0]*rv[0] + k[1]*rv[1] + k[2]*rv[2];
    #pragma unroll
    for (int l = 0; l < 3; ++l) { q[l] -= dq * rv[l]; k[l] -= dk * rv[l]; }
    dq = 0.f; dk = 0.f;
    #pragma unroll
    for (int l = 3; l < 8; ++l) { dq += q[l]*rv[l]; dk += k[l]*rv[l]; }
    #pragma unroll
    for (int l = 3; l < 8; ++l) { q[l] -= dq * rv[l]; k[l] -= dk * rv[l]; }
    dq = 0.f; dk = 0.f;
    #pragma unroll
    for (int l = 8; l < 15; ++l) { dq += q[l]*rv[l]; dk += k[l]*rv[l]; }
    #pragma unroll
    for (int l = 8; l < 15; ++l) { q[l] -= dq * rv[l]; k[l] -= dk * rv[l]; }

    float w = 0.f;
    #pragma unroll
    for (int l = 0; l < 15; ++l) w = fmaf(q[l], k[l], w);

    float s = w, s2 = w * w;
    s += __shfl_xor(s, 1);  s2 += __shfl_xor(s2, 1);
    s += __shfl_xor(s, 2);  s2 += __shfl_xor(s2, 2);
    s += __shfl_xor(s, 4);  s2 += __shfl_xor(s2, 4);
    s += __shfl_xor(s, 8);  s2 += __shfl_xor(s2, 8);
    s += __shfl_xor(s, 16); s2 += __shfl_xor(s2, 16);
    const float mu  = s * (1.f / 32.f);
    const float var = s2 * (1.f / 32.f) - mu * mu;
    const float wnv = (w - mu) * rsqrtf(var + LN_EPS) * g + bb;
    wn[(size_t)e * 32 + r] = f2bf(wnv);
}

// ---------------------------------------------------------------------------
// Kernel 3: barrier-free streaming MFMA GEMMs + epilogue, D[n][edge] layout.
// 64 edges PER WAVE (4 B-frag groups): weight traffic per edge halves vs
// round 5 and each wave fronts 16 independent t_ij loads (MLP). Per-wave
// 16KB LDS h panel (XOR-swizzled), no __syncthreads.
// ---------------------------------------------------------------------------
__global__ __launch_bounds__(256) void edge_kernel(
    const float* __restrict__ t_ij,
    const unsigned short* __restrict__ wn,
    const unsigned short* __restrict__ Wtw, const float* __restrict__ b_w,
    const unsigned short* __restrict__ Wt1, const float* __restrict__ b_t1,
    const unsigned short* __restrict__ Wt2, const float* __restrict__ b_t2,
    float* __restrict__ out)
{
    __shared__ __align__(16) unsigned short Hp[4][64 * 128];  // 16KB per wave

    const int tid  = threadIdx.x;
    const int lane = tid & 63;
    const int wv   = tid >> 6;
    const int l15  = lane & 15;
    const int lk   = lane >> 4;
    const int tile = (blockIdx.x * 4 + wv) * 64;
    char* hp = (char*)&Hp[wv][0];
    const int swz = (l15 & 7) << 4;

    // ---- B-frags: t_ij edges direct from global (lane = edge col) ----
    bf16x8 a1[4][4];
    #pragma unroll
    for (int kt = 0; kt < 4; ++kt)
        #pragma unroll
        for (int rt = 0; rt < 4; ++rt) {
            const float* p = t_ij + (size_t)(tile + rt * 16 + l15) * 128
                           + kt * 32 + lk * 8;
            a1[kt][rt] = pack8(*(const float4*)p, *(const float4*)(p + 4));
        }

    // ---- wn B-frags ----
    bf16x8 wnf[4];
    #pragma unroll
    for (int rt = 0; rt < 4; ++rt)
        wnf[rt] = *(const bf16x8*)&wn[(size_t)(tile + rt * 16 + l15) * 32 + lk * 8];

    // ---- GEMM1: h = silu(t @ W_t1 + b_t1) -> D[n][edge] -> h panel ----
    #pragma unroll
    for (int ct = 0; ct < 8; ++ct) {
        bf16x8 w1f[4];
        #pragma unroll
        for (int kt = 0; kt < 4; ++kt)
            w1f[kt] = *(const bf16x8*)&Wt1[(size_t)(ct * 16 + l15) * 128
                                           + kt * 32 + lk * 8];
        f32x4 ac[4];
        #pragma unroll
        for (int rt = 0; rt < 4; ++rt) ac[rt] = (f32x4){0.f, 0.f, 0.f, 0.f};
        #pragma unroll
        for (int kt = 0; kt < 4; ++kt)
            #pragma unroll
            for (int rt = 0; rt < 4; ++rt)
                ac[rt] = mfma16(w1f[kt], a1[kt][rt], ac[rt]);

        const float4 bt1 = *(const float4*)&b_t1[ct * 16 + lk * 4];
        #pragma unroll
        for (int rt = 0; rt < 4; ++rt) {
            uint2 hh;
            hh.x = pk2(silu_f(ac[rt][0] + bt1.x), silu_f(ac[rt][1] + bt1.y));
            hh.y = pk2(silu_f(ac[rt][2] + bt1.z), silu_f(ac[rt][3] + bt1.w));
            *(uint2*)(hp + (((rt * 16 + l15) * 256 + ct * 32 + lk * 8) ^ swz)) = hh;
        }
    }

    // ---- a2 B-frags from h panel (wave-local; compiler inserts lgkmcnt) ----
    bf16x8 a2[4][4];
    #pragma unroll
    for (int kt = 0; kt < 4; ++kt)
        #pragma unroll
        for (int rt = 0; rt < 4; ++rt)
            a2[kt][rt] = *(const bf16x8*)(hp +
                (((rt * 16 + l15) * 256 + kt * 64 + lk * 16) ^ swz));

    // ---- GEMM2 + dw + epilogue ----
    #pragma unroll
    for (int ct = 0; ct < 8; ++ct) {
        bf16x8 w2f[4];
        #pragma unroll
        for (int kt = 0; kt < 4; ++kt)
            w2f[kt] = *(const bf16x8*)&Wt2[(size_t)(ct * 16 + l15) * 128
                                           + kt * 32 + lk * 8];
        bf16x8 wwf = *(const bf16x8*)&Wtw[(ct * 16 + l15) * 32 + lk * 8];

        f32x4 o[4], d[4];
        #pragma unroll
        for (int rt = 0; rt < 4; ++rt) o[rt] = (f32x4){0.f, 0.f, 0.f, 0.f};
        #pragma unroll
        for (int kt = 0; kt < 4; ++kt)
            #pragma unroll
            for (int rt = 0; rt < 4; ++rt)
                o[rt] = mfma16(w2f[kt], a2[kt][rt], o[rt]);
        #pragma unroll
        for (int rt = 0; rt < 4; ++rt)
            d[rt] = mfma16(wwf, wnf[rt], (f32x4){0.f, 0.f, 0.f, 0.f});

        const float4 bwv = *(const float4*)&b_w[ct * 16 + lk * 4];
        const float4 b2v = *(const float4*)&b_t2[ct * 16 + lk * 4];
        #pragma unroll
        for (int rt = 0; rt < 4; ++rt) {
            float4 s;
            s.x = (d[rt][0] + bwv.x) * silu_f(o[rt][0] + b2v.x);
            s.y = (d[rt][1] + bwv.y) * silu_f(o[rt][1] + b2v.y);
            s.z = (d[rt][2] + bwv.z) * silu_f(o[rt][2] + b2v.z);
            s.w = (d[rt][3] + bwv.w) * silu_f(o[rt][3] + b2v.w);
            *(float4*)&out[(size_t)(tile + rt * 16 + l15) * 128 + ct * 16 + lk * 4] = s;
        }
    }
}

extern "C" void kernel_launch(void* const* d_in, const int* in_sizes, int n_in,
                              void* d_out, int out_size, void* d_ws, size_t ws_size,
                              hipStream_t stream) {
    (void)in_sizes; (void)n_in; (void)out_size; (void)ws_size;
    const float* X0   = (const float*)d_in[0];
    const float* X1   = (const float*)d_in[1];
    const float* X2   = (const float*)d_in[2];
    const float* t_ij = (const float*)d_in[3];
    const float* r0   = (const float*)d_in[4];
    const float* r1   = (const float*)d_in[5];
    const float* r2   = (const float*)d_in[6];
    const int*   eidx = (const int*)d_in[7];
    const float* Wvq  = (const float*)d_in[8];
    const float* Wvk0 = (const float*)d_in[9];
    const float* Wvk1 = (const float*)d_in[10];
    const float* Wvk2 = (const float*)d_in[11];
    const float* ln_g = (const float*)d_in[12];
    const float* ln_b = (const float*)d_in[13];
    const float* W_w  = (const float*)d_in[14];
    const float* b_w  = (const float*)d_in[15];
    const float* W_t1 = (const float*)d_in[16];
    const float* b_t1 = (const float*)d_in[17];
    const float* W_t2 = (const float*)d_in[18];
    const float* b_t2 = (const float*)d_in[19];
    float* out = (float*)d_out;

    unsigned short* eq   = (unsigned short*)d_ws;          // [N][32][16] bf16
    unsigned short* ek   = eq  + (size_t)N_NODES * 512;
    unsigned short* wn   = ek  + (size_t)N_NODES * 512;    // [E,32] bf16
    unsigned short* Wtw  = wn  + (size_t)N_EDGES * 32;
    unsigned short* Wt1b = Wtw  + 4096;
    unsigned short* Wt2b = Wt1b + 16384;
    unsigned short* Wqt  = Wt2b + 16384;
    unsigned short* Wk0t = Wqt  + 4096;
    unsigned short* Wk1t = Wk0t + 4096;
    unsigned short* Wk2t = Wk1t + 4096;

    prep_kernel<<<64, 256, 0, stream>>>(W_w, W_t1, W_t2, Wvq, Wvk0, Wvk1, Wvk2,
                                        Wtw, Wt1b, Wt2b, Wqt, Wk0t, Wk1t, Wk2t);
    proj_kernel<<<1920, 256, 0, stream>>>(X0, X1, X2, Wqt, Wk0t, Wk1t, Wk2t,
                                          eq, ek);
    wn_kernel<<<N_EDGES / 8, 256, 0, stream>>>(eq, ek, r0, r1, r2, eidx,
                                               ln_g, ln_b, wn);
    edge_kernel<<<N_EDGES / 256, 256, 0, stream>>>(t_ij, wn, Wtw, b_w,
                                                   Wt1b, b_t1, Wt2b, b_t2, out);
}